// Round 8
// baseline (541.378 us; speedup 1.0000x reference)
//
#include <hip/hip_runtime.h>
#include <math.h>

#define H 128
#define RBITS 13
#define RSIZE 8192        // nodes per range (32 KB packed LDS histogram)
#define NCHUNK 96         // edge chunks

typedef __attribute__((ext_vector_type(8))) short bf16x8;
typedef __attribute__((ext_vector_type(4))) float f32x4;

__device__ inline unsigned short f2bf(float f) {      // RNE float->bf16
  unsigned u = __float_as_uint(f);
  return (unsigned short)((u + 0x7FFF + ((u >> 16) & 1)) >> 16);
}

// ---------------- histogram: packed src|dst counts, per-(range,chunk), LDS atomics only ----------------
__global__ __launch_bounds__(256) void k_hist(const int* __restrict__ src,
                                              const int* __restrict__ dst,
                                              int* __restrict__ ppack, int E) {
  int r = blockIdx.x / NCHUNK, c = blockIdx.x % NCHUNK;
  int base = r << RBITS;
  __shared__ int h[RSIZE];                 // low16 = src count, high16 = dst count
  for (int i = threadIdx.x; i < RSIZE; i += 256) h[i] = 0;
  __syncthreads();
  int e0 = (int)(((long long)E * c) / NCHUNK);
  int e1 = (int)(((long long)E * (c + 1)) / NCHUNK);
  for (int e = e0 + threadIdx.x; e < e1; e += 256) {
    unsigned ls = (unsigned)(src[e] - base);
    if (ls < RSIZE) atomicAdd(&h[ls], 1);
    unsigned ld = (unsigned)(dst[e] - base);
    if (ld < RSIZE) atomicAdd(&h[ld], 0x10000);
  }
  __syncthreads();
  int* p = ppack + (((size_t)(r * NCHUNK + c)) << RBITS);
  for (int i = threadIdx.x; i < RSIZE; i += 256) p[i] = h[i];
}

// ---------------- reduce: unpack counts -> degrees/norms; rewrite ppack as dst chunk-prefix ----------------
__global__ void k_reduce(int* __restrict__ ppack,
                         int* __restrict__ ind, float* __restrict__ onorm,
                         float* __restrict__ inorm, int N) {
  int i = blockIdx.x * blockDim.x + threadIdx.x;
  if (i >= N) return;
  int r = i >> RBITS, l = i & (RSIZE - 1);
  size_t rb = ((size_t)r * NCHUNK) << RBITS;
  int sumS = 0, run = 0;
  for (int c = 0; c < NCHUNK; ++c) {
    size_t idx = rb + ((size_t)c << RBITS) + l;
    int v = ppack[idx];
    sumS += v & 0xFFFF;
    ppack[idx] = run;           // exclusive dst prefix over chunks
    run += (v >> 16) & 0xFFFF;
  }
  ind[i] = run;
  int od = sumS < 1 ? 1 : sumS;
  int id = run < 1 ? 1 : run;
  onorm[i] = rsqrtf((float)od);
  inorm[i] = rsqrtf((float)id);
}

// ---------------- CSR row_ptr: three-phase multi-block exclusive scan ----------------
__global__ __launch_bounds__(1024) void k_scan_blocks(const int* __restrict__ counts,
                                                      int* __restrict__ row_ptr,
                                                      int* __restrict__ blk_sums, int N) {
  __shared__ int buf[1024];
  int i = blockIdx.x * 1024 + threadIdx.x;
  int v = (i < N) ? counts[i] : 0;
  buf[threadIdx.x] = v;
  __syncthreads();
#pragma unroll
  for (int off = 1; off < 1024; off <<= 1) {
    int t = 0;
    if (threadIdx.x >= off) t = buf[threadIdx.x - off];
    __syncthreads();
    if (threadIdx.x >= off) buf[threadIdx.x] += t;
    __syncthreads();
  }
  if (i < N) row_ptr[i] = buf[threadIdx.x] - v;  // local exclusive
  if (threadIdx.x == 1023) blk_sums[blockIdx.x] = buf[1023];
}

__global__ __launch_bounds__(1024) void k_scan_tops(int* __restrict__ blk_sums,
                                                    int* __restrict__ blk_offs,
                                                    int* __restrict__ row_ptr,
                                                    int nb, int N) {
  __shared__ int buf[1024];
  int v = (threadIdx.x < nb) ? blk_sums[threadIdx.x] : 0;
  buf[threadIdx.x] = v;
  __syncthreads();
#pragma unroll
  for (int off = 1; off < 1024; off <<= 1) {
    int t = 0;
    if (threadIdx.x >= off) t = buf[threadIdx.x - off];
    __syncthreads();
    if (threadIdx.x >= off) buf[threadIdx.x] += t;
    __syncthreads();
  }
  if (threadIdx.x < nb) blk_offs[threadIdx.x] = buf[threadIdx.x] - v;
  if (threadIdx.x == 1023) row_ptr[N] = buf[1023];
}

__global__ void k_scan_add(int* __restrict__ row_ptr, const int* __restrict__ blk_offs, int N) {
  int i = blockIdx.x * blockDim.x + threadIdx.x;
  if (i < N) row_ptr[i] += blk_offs[i >> 10];
}

// ---------------- CSR fill: LDS cursors seeded from row_ptr + chunk prefix ----------------
__global__ __launch_bounds__(256) void k_fill_nr(const int* __restrict__ src,
                                                 const int* __restrict__ dst,
                                                 const int* __restrict__ row_ptr,
                                                 const int* __restrict__ ppfx,
                                                 int* __restrict__ csr, int N, int E) {
  int r = blockIdx.x / NCHUNK, c = blockIdx.x % NCHUNK;
  int base = r << RBITS;
  __shared__ int cur[RSIZE];
  const int* pd = ppfx + (((size_t)(r * NCHUNK + c)) << RBITS);
  for (int i = threadIdx.x; i < RSIZE; i += 256) {
    int node = base + i;
    cur[i] = (node < N) ? (row_ptr[node] + pd[i]) : 0;
  }
  __syncthreads();
  int e0 = (int)(((long long)E * c) / NCHUNK);
  int e1 = (int)(((long long)E * (c + 1)) / NCHUNK);
  for (int e = e0 + threadIdx.x; e < e1; e += 256) {
    unsigned ld = (unsigned)(dst[e] - base);
    if (ld < RSIZE) {
      int pos = atomicAdd(&cur[ld], 1);   // LDS atomic
      csr[pos] = src[e];
    }
  }
}

// ---------------- split-bf16 MFMA GEMM: out[N x 128] = act(A[N x K] @ W[K x 128] + b) ----------------
// A,W decomposed hi+lo bf16; acc = Ah*Wh + Al*Wh + Ah*Wl in fp32 MFMA (~17-bit mantissa).
// Block: 256 thr = 4 waves, 64 rows. W hi/lo staged once in LDS in B-frag swizzled order;
// A frags straight from global (fp32 -> hi/lo in regs). No barriers in the K-loop.
// Frag maps (verified m89/m120): A[m=lane&15][k=quad*8+j]; B mirrored; C/D col=lane&15,row=quad*4+reg.
// In-place safe (block reads only its own 64 rows; writes after all reads).
__global__ __launch_bounds__(256) void k_gemm_mfma(const float* __restrict__ A,
                                                   const float* __restrict__ W,
                                                   const float* __restrict__ bias,
                                                   const float* __restrict__ onorm,
                                                   float* __restrict__ out_f,
                                                   unsigned short* __restrict__ out_bf,
                                                   int N, int K, int do_silu) {
  extern __shared__ short smem[];
  const int KT = (K + 31) >> 5;
  short* whi = smem;                 // [KT*8 frags][64 lanes][8 shorts]
  short* wlo = smem + (size_t)KT * 4096;
  const int t = threadIdx.x;

  // zero ragged last k-slab so padded frags contribute 0
  if (K & 31) {
    for (int i = t; i < 4096; i += 256) {
      whi[(size_t)(KT - 1) * 4096 + i] = 0;
      wlo[(size_t)(KT - 1) * 4096 + i] = 0;
    }
    __syncthreads();
  }
  // stage W: coalesced float4 reads, swizzled hi/lo LDS writes
  for (int idx4 = t; idx4 < K * 32; idx4 += 256) {
    int k = idx4 >> 5;
    int n4 = (idx4 & 31) << 2;
    float4 wv = *(const float4*)(W + (size_t)k * H + n4);
    int kt = k >> 5, q2 = (k >> 3) & 3, j = k & 7;
    float wf[4] = {wv.x, wv.y, wv.z, wv.w};
#pragma unroll
    for (int i = 0; i < 4; ++i) {
      int n = n4 + i;
      int ct = n >> 4;
      int ln = (q2 << 4) | (n & 15);
      unsigned short hi = f2bf(wf[i]);
      float hif = __uint_as_float((unsigned)hi << 16);
      unsigned short lo = f2bf(wf[i] - hif);
      size_t o = ((size_t)(kt * 8 + ct) * 64 + ln) * 8 + j;
      whi[o] = (short)hi;
      wlo[o] = (short)lo;
    }
  }
  __syncthreads();

  const int w = t >> 6;        // wave 0..3
  const int l = t & 63;        // lane
  const int q = l >> 4;        // quad
  const int m = l & 15;
  const int rbase = blockIdx.x * 64 + w * 16;
  const int row = rbase + m;   // A-load row
  const bool rowOK = row < N;
  const float* Ap = A + (size_t)(rowOK ? row : 0) * K;

  f32x4 acc[8];
#pragma unroll
  for (int ct = 0; ct < 8; ++ct) acc[ct] = (f32x4){0.f, 0.f, 0.f, 0.f};

  for (int kt = 0; kt < KT; ++kt) {
    int kbase = kt * 32 + q * 8;
    float f[8];
    if (rowOK && kbase + 8 <= K) {
      float4 f0 = *(const float4*)(Ap + kbase);
      float4 f1 = *(const float4*)(Ap + kbase + 4);
      f[0] = f0.x; f[1] = f0.y; f[2] = f0.z; f[3] = f0.w;
      f[4] = f1.x; f[5] = f1.y; f[6] = f1.z; f[7] = f1.w;
    } else {
#pragma unroll
      for (int j = 0; j < 8; ++j)
        f[j] = (rowOK && kbase + j < K) ? Ap[kbase + j] : 0.f;
    }
    union { bf16x8 v; short s[8]; } ah, al;
#pragma unroll
    for (int j = 0; j < 8; ++j) {
      unsigned short hi = f2bf(f[j]);
      ah.s[j] = (short)hi;
      float hif = __uint_as_float((unsigned)hi << 16);
      al.s[j] = (short)f2bf(f[j] - hif);
    }
    const short* bh_base = whi + ((size_t)(kt * 8) * 64 + l) * 8;
    const short* bl_base = wlo + ((size_t)(kt * 8) * 64 + l) * 8;
#pragma unroll
    for (int ct = 0; ct < 8; ++ct) {
      bf16x8 bh = *(const bf16x8*)(bh_base + (size_t)ct * 512);
      bf16x8 bl = *(const bf16x8*)(bl_base + (size_t)ct * 512);
      acc[ct] = __builtin_amdgcn_mfma_f32_16x16x32_bf16(ah.v, bh, acc[ct], 0, 0, 0);
      acc[ct] = __builtin_amdgcn_mfma_f32_16x16x32_bf16(al.v, bh, acc[ct], 0, 0, 0);
      acc[ct] = __builtin_amdgcn_mfma_f32_16x16x32_bf16(ah.v, bl, acc[ct], 0, 0, 0);
    }
  }

  // epilogue: C/D row = rbase + q*4 + r, col = ct*16 + m
  int orow[4]; bool ok[4]; float on_[4];
#pragma unroll
  for (int r = 0; r < 4; ++r) {
    orow[r] = rbase + q * 4 + r;
    ok[r] = orow[r] < N;
    on_[r] = (out_bf && ok[r]) ? onorm[orow[r]] : 0.f;
  }
#pragma unroll
  for (int ct = 0; ct < 8; ++ct) {
    int col = ct * 16 + m;
    float bcol = bias[col];
    if (out_bf) {
#pragma unroll
      for (int r = 0; r < 4; ++r) {
        if (ok[r]) {
          float v = acc[ct][r] + bcol;
          v = v / (1.f + expf(-v));     // silu
          out_bf[(size_t)orow[r] * H + col] = f2bf(v * on_[r]);
        }
      }
    } else {
#pragma unroll
      for (int r = 0; r < 4; ++r) {
        if (ok[r]) {
          float v = acc[ct][r] + bcol;
          if (do_silu) v = v / (1.f + expf(-v));
          out_f[(size_t)orow[r] * H + col] = v;
        }
      }
    }
  }
}

// ---------------- gather (bf16 rows, onorm pre-folded): agg[v] = inorm[v]*sum h[src] ----------------
__global__ __launch_bounds__(64) void k_gather_bf(const unsigned* __restrict__ hb, // N x 64 words
                                                  const int* __restrict__ csr_src,
                                                  const int* __restrict__ row_ptr,
                                                  const float* __restrict__ inorm,
                                                  float* __restrict__ agg, int N) {
  int v = blockIdx.x;
  int t = threadIdx.x;
  int b = row_ptr[v], e = row_ptr[v + 1];
  float ax = 0.f, ay = 0.f;
  for (int i = b; i < e; ++i) {
    int s = csr_src[i];
    unsigned p = hb[(size_t)s * 64 + t];
    ax += __uint_as_float(p << 16);           // col 2t
    ay += __uint_as_float(p & 0xFFFF0000u);   // col 2t+1
  }
  float inn = inorm[v];
  *(float2*)(agg + (size_t)v * H + t * 2) = make_float2(ax * inn, ay * inn);
}

// ---------------- pooling: segment-sum over sorted graph_ids ----------------
__global__ __launch_bounds__(128) void k_pool(const float* __restrict__ h,
                                              const int* __restrict__ gid,
                                              float* pooled, int N) {
  int c = threadIdx.x;
  int v0 = blockIdx.x * 128;
  int vend = v0 + 128; if (vend > N) vend = N;
  if (v0 >= N) return;
  int cur = gid[v0];
  float acc = 0.f;
  for (int v = v0; v < vend; ++v) {
    int g = gid[v];
    if (g != cur) {
      atomicAdd(&pooled[(size_t)cur * H + c], acc);
      acc = 0.f; cur = g;
    }
    acc += h[(size_t)v * H + c];
  }
  atomicAdd(&pooled[(size_t)cur * H + c], acc);
}

// ---------------- final ff ----------------
__global__ __launch_bounds__(128) void k_ff(const float* __restrict__ pooled,
                                            const float* __restrict__ Wff,
                                            const float* __restrict__ bff,
                                            float* __restrict__ out, int G) {
  int g = blockIdx.x;
  int t = threadIdx.x;
  float v = pooled[(size_t)g * H + t] * Wff[t];
#pragma unroll
  for (int off = 32; off > 0; off >>= 1) v += __shfl_down(v, off, 64);
  __shared__ float red[2];
  if ((t & 63) == 0) red[t >> 6] = v;
  __syncthreads();
  if (t == 0) out[g] = red[0] + red[1] + bff[0];
}

extern "C" void kernel_launch(void* const* d_in, const int* in_sizes, int n_in,
                              void* d_out, int out_size, void* d_ws, size_t ws_size,
                              hipStream_t stream) {
  const float* x     = (const float*)d_in[0];
  const float* W_in  = (const float*)d_in[1];
  const float* b_in  = (const float*)d_in[2];
  const float* W_g0  = (const float*)d_in[3];
  const float* b_g0  = (const float*)d_in[4];
  const float* W_g1  = (const float*)d_in[5];
  const float* b_g1  = (const float*)d_in[6];
  const float* W_g2  = (const float*)d_in[7];
  const float* b_g2  = (const float*)d_in[8];
  const float* W_out = (const float*)d_in[9];
  const float* b_out = (const float*)d_in[10];
  const float* W_ff  = (const float*)d_in[11];
  const float* b_ff  = (const float*)d_in[12];
  const int* src = (const int*)d_in[13];
  const int* dst = (const int*)d_in[14];
  const int* gid = (const int*)d_in[15];
  float* out = (float*)d_out;

  const int N = in_sizes[15];          // 50000
  const int E = in_sizes[13];          // 600000
  const int K_IN = in_sizes[1] / H;    // 74
  const int G = out_size;              // 500

  char* ws = (char*)d_ws;
  size_t off = 0;
  auto alloc = [&](size_t bytes) -> void* {
    void* p = ws + off;
    off = (off + bytes + 255) & ~(size_t)255;
    return p;
  };
  float*          agg  = (float*)alloc((size_t)N * H * 4);          // fp32 gather out / h3 / hfinal
  unsigned short* hb   = (unsigned short*)alloc((size_t)N * H * 2); // bf16 gather in
  float* onorm   = (float*)alloc((size_t)N * 4);
  float* inorm   = (float*)alloc((size_t)N * 4);
  int*   ind     = (int*)alloc((size_t)N * 4);
  int*   row_ptr = (int*)alloc((size_t)(N + 1) * 4);
  int*   csr     = (int*)alloc((size_t)E * 4);
  float* pooled  = (float*)alloc((size_t)G * H * 4);
  int nb = (N + 1023) / 1024;
  int*   blk_sums = (int*)alloc((size_t)nb * 4);
  int*   blk_offs = (int*)alloc((size_t)nb * 4);

  // packed hist partials alias agg (dead until first gather, long after CSR build):
  // nr*NCHUNK*RSIZE ints = 7*96*8192*4 = 22.0 MB <= N*H*4 = 25.6 MB.
  int nr = (N + RSIZE - 1) / RSIZE;
  int* ppack = (int*)agg;

  hipMemsetAsync(pooled, 0, (size_t)G * H * 4, stream);

  k_hist<<<nr * NCHUNK, 256, 0, stream>>>(src, dst, ppack, E);
  k_reduce<<<(N + 255) / 256, 256, 0, stream>>>(ppack, ind, onorm, inorm, N);
  k_scan_blocks<<<nb, 1024, 0, stream>>>(ind, row_ptr, blk_sums, N);
  k_scan_tops<<<1, 1024, 0, stream>>>(blk_sums, blk_offs, row_ptr, nb, N);
  k_scan_add<<<(N + 255) / 256, 256, 0, stream>>>(row_ptr, blk_offs, N);
  k_fill_nr<<<nr * NCHUNK, 256, 0, stream>>>(src, dst, row_ptr, ppack, csr, N, E);

  int gblk = (N + 63) / 64;
  auto shb = [](int K) { return (size_t)((K + 31) >> 5) * 4096 * 2 * sizeof(short); };

  // embedding_in: hb0 = bf16(silu(x @ W_in + b_in) * onorm)
  k_gemm_mfma<<<gblk, 256, shb(K_IN), stream>>>(x, W_in, b_in, onorm, nullptr, hb, N, K_IN, 1);

  // layer 0
  k_gather_bf<<<N, 64, 0, stream>>>((const unsigned*)hb, csr, row_ptr, inorm, agg, N);
  k_gemm_mfma<<<gblk, 256, shb(H), stream>>>(agg, W_g0, b_g0, onorm, nullptr, hb, N, H, 1);
  // layer 1
  k_gather_bf<<<N, 64, 0, stream>>>((const unsigned*)hb, csr, row_ptr, inorm, agg, N);
  k_gemm_mfma<<<gblk, 256, shb(H), stream>>>(agg, W_g1, b_g1, onorm, nullptr, hb, N, H, 1);
  // layer 2: output feeds GEMM (sequential) -> fp32 in place
  k_gather_bf<<<N, 64, 0, stream>>>((const unsigned*)hb, csr, row_ptr, inorm, agg, N);
  k_gemm_mfma<<<gblk, 256, shb(H), stream>>>(agg, W_g2, b_g2, nullptr, agg, nullptr, N, H, 1);

  // embedding_out (no act), in-place
  k_gemm_mfma<<<gblk, 256, shb(H), stream>>>(agg, W_out, b_out, nullptr, agg, nullptr, N, H, 0);

  k_pool<<<(N + 127) / 128, 128, 0, stream>>>(agg, gid, pooled, N);
  k_ff<<<G, 128, 0, stream>>>(pooled, W_ff, b_ff, out, G);
}

// Round 9
// 418.613 us; speedup vs baseline: 1.2933x; 1.2933x over previous
//
#include <hip/hip_runtime.h>
#include <math.h>

#define H 128
#define RBITS 13
#define RSIZE 8192        // nodes per range (32 KB packed LDS histogram)
#define NCHUNK 96         // edge chunks

typedef __attribute__((ext_vector_type(8))) short bf16x8;
typedef __attribute__((ext_vector_type(4))) float f32x4;

__device__ inline unsigned short f2bf(float f) {      // RNE float->bf16
  unsigned u = __float_as_uint(f);
  return (unsigned short)((u + 0x7FFF + ((u >> 16) & 1)) >> 16);
}

// ---------------- histogram: packed src|dst counts, per-(range,chunk), LDS atomics only ----------------
__global__ __launch_bounds__(256) void k_hist(const int* __restrict__ src,
                                              const int* __restrict__ dst,
                                              int* __restrict__ ppack, int E) {
  int r = blockIdx.x / NCHUNK, c = blockIdx.x % NCHUNK;
  int base = r << RBITS;
  __shared__ int h[RSIZE];                 // low16 = src count, high16 = dst count
  for (int i = threadIdx.x; i < RSIZE; i += 256) h[i] = 0;
  __syncthreads();
  int e0 = (int)(((long long)E * c) / NCHUNK);
  int e1 = (int)(((long long)E * (c + 1)) / NCHUNK);
  for (int e = e0 + threadIdx.x; e < e1; e += 256) {
    unsigned ls = (unsigned)(src[e] - base);
    if (ls < RSIZE) atomicAdd(&h[ls], 1);
    unsigned ld = (unsigned)(dst[e] - base);
    if (ld < RSIZE) atomicAdd(&h[ld], 0x10000);
  }
  __syncthreads();
  int* p = ppack + (((size_t)(r * NCHUNK + c)) << RBITS);
  for (int i = threadIdx.x; i < RSIZE; i += 256) p[i] = h[i];
}

// ---------------- reduce: unpack counts -> degrees/norms; rewrite ppack as dst chunk-prefix ----------------
__global__ void k_reduce(int* __restrict__ ppack,
                         int* __restrict__ ind, float* __restrict__ onorm,
                         float* __restrict__ inorm, int N) {
  int i = blockIdx.x * blockDim.x + threadIdx.x;
  if (i >= N) return;
  int r = i >> RBITS, l = i & (RSIZE - 1);
  size_t rb = ((size_t)r * NCHUNK) << RBITS;
  int sumS = 0, run = 0;
  for (int c = 0; c < NCHUNK; ++c) {
    size_t idx = rb + ((size_t)c << RBITS) + l;
    int v = ppack[idx];
    sumS += v & 0xFFFF;
    ppack[idx] = run;           // exclusive dst prefix over chunks
    run += (v >> 16) & 0xFFFF;
  }
  ind[i] = run;
  int od = sumS < 1 ? 1 : sumS;
  int id = run < 1 ? 1 : run;
  onorm[i] = rsqrtf((float)od);
  inorm[i] = rsqrtf((float)id);
}

// ---------------- CSR row_ptr: three-phase multi-block exclusive scan ----------------
__global__ __launch_bounds__(1024) void k_scan_blocks(const int* __restrict__ counts,
                                                      int* __restrict__ row_ptr,
                                                      int* __restrict__ blk_sums, int N) {
  __shared__ int buf[1024];
  int i = blockIdx.x * 1024 + threadIdx.x;
  int v = (i < N) ? counts[i] : 0;
  buf[threadIdx.x] = v;
  __syncthreads();
#pragma unroll
  for (int off = 1; off < 1024; off <<= 1) {
    int t = 0;
    if (threadIdx.x >= off) t = buf[threadIdx.x - off];
    __syncthreads();
    if (threadIdx.x >= off) buf[threadIdx.x] += t;
    __syncthreads();
  }
  if (i < N) row_ptr[i] = buf[threadIdx.x] - v;  // local exclusive
  if (threadIdx.x == 1023) blk_sums[blockIdx.x] = buf[1023];
}

__global__ __launch_bounds__(1024) void k_scan_tops(int* __restrict__ blk_sums,
                                                    int* __restrict__ blk_offs,
                                                    int* __restrict__ row_ptr,
                                                    int nb, int N) {
  __shared__ int buf[1024];
  int v = (threadIdx.x < nb) ? blk_sums[threadIdx.x] : 0;
  buf[threadIdx.x] = v;
  __syncthreads();
#pragma unroll
  for (int off = 1; off < 1024; off <<= 1) {
    int t = 0;
    if (threadIdx.x >= off) t = buf[threadIdx.x - off];
    __syncthreads();
    if (threadIdx.x >= off) buf[threadIdx.x] += t;
    __syncthreads();
  }
  if (threadIdx.x < nb) blk_offs[threadIdx.x] = buf[threadIdx.x] - v;
  if (threadIdx.x == 1023) row_ptr[N] = buf[1023];
}

__global__ void k_scan_add(int* __restrict__ row_ptr, const int* __restrict__ blk_offs, int N) {
  int i = blockIdx.x * blockDim.x + threadIdx.x;
  if (i < N) row_ptr[i] += blk_offs[i >> 10];
}

// ---------------- CSR fill: LDS cursors seeded from row_ptr + chunk prefix ----------------
__global__ __launch_bounds__(256) void k_fill_nr(const int* __restrict__ src,
                                                 const int* __restrict__ dst,
                                                 const int* __restrict__ row_ptr,
                                                 const int* __restrict__ ppfx,
                                                 int* __restrict__ csr, int N, int E) {
  int r = blockIdx.x / NCHUNK, c = blockIdx.x % NCHUNK;
  int base = r << RBITS;
  __shared__ int cur[RSIZE];
  const int* pd = ppfx + (((size_t)(r * NCHUNK + c)) << RBITS);
  for (int i = threadIdx.x; i < RSIZE; i += 256) {
    int node = base + i;
    cur[i] = (node < N) ? (row_ptr[node] + pd[i]) : 0;
  }
  __syncthreads();
  int e0 = (int)(((long long)E * c) / NCHUNK);
  int e1 = (int)(((long long)E * (c + 1)) / NCHUNK);
  for (int e = e0 + threadIdx.x; e < e1; e += 256) {
    unsigned ld = (unsigned)(dst[e] - base);
    if (ld < RSIZE) {
      int pos = atomicAdd(&cur[ld], 1);   // LDS atomic
      csr[pos] = src[e];
    }
  }
}

// ---------------- weight split: fp32 W[Kx128] -> hi/lo bf16 in B-frag order, once per launch ----------------
// Frag order: o = ((kt*8 + ct)*64 + ln)*8 + j; element k = kt*32 + (ln>>4)*8 + j, n = ct*16 + (ln&15).
struct WSplitArgs {
  const float* W[5];
  int K[5];
  int off[6];     // in shorts, cumulative frag-space offsets
};
__global__ __launch_bounds__(256) void k_wsplit(WSplitArgs a, short* __restrict__ hi_buf,
                                                short* __restrict__ lo_buf) {
  int idx = blockIdx.x * 256 + threadIdx.x;
  if (idx >= a.off[5]) return;
  int wsel = 0;
  while (idx >= a.off[wsel + 1]) ++wsel;
  int lidx = idx - a.off[wsel];
  int j  = lidx & 7;
  int ln = (lidx >> 3) & 63;
  int ct = (lidx >> 9) & 7;
  int kt = lidx >> 12;
  int k = (kt << 5) | ((ln >> 4) << 3) | j;
  int n = (ct << 4) | (ln & 15);
  float v = (k < a.K[wsel]) ? a.W[wsel][(size_t)k * H + n] : 0.f;
  unsigned short hi = f2bf(v);
  float hif = __uint_as_float((unsigned)hi << 16);
  unsigned short lo = f2bf(v - hif);
  hi_buf[idx] = (short)hi;
  lo_buf[idx] = (short)lo;
}

// ---------------- split-bf16 MFMA GEMM: out[N x 128] = act(A[N x K] @ W[K x 128] + b) ----------------
// A fp32 -> hi/lo bf16 in regs; W pre-split frags read from global (L2-hot, shared by all blocks).
// acc = Ah*Wh + Al*Wh + Ah*Wl in fp32 MFMA (~17-bit mantissa). No LDS, no barriers.
// Block: 256 thr = 4 waves, each wave 16 rows x 128 cols (8 accs).
// Frag maps (verified m89/m120): A[m=lane&15][k=quad*8+j]; C/D col=lane&15,row=quad*4+reg.
// In-place safe (block reads only its own rows; W/bias never aliased).
__global__ __launch_bounds__(256) void k_gemm_mfma(const float* __restrict__ A,
                                                   const short* __restrict__ whi,
                                                   const short* __restrict__ wlo,
                                                   const float* __restrict__ bias,
                                                   const float* __restrict__ onorm,
                                                   float* __restrict__ out_f,
                                                   unsigned short* __restrict__ out_bf,
                                                   int N, int K, int do_silu) {
  const int t = threadIdx.x;
  const int w = t >> 6;        // wave 0..3
  const int l = t & 63;        // lane
  const int q = l >> 4;        // quad
  const int m = l & 15;
  const int rbase = blockIdx.x * 64 + w * 16;
  const int row = rbase + m;   // A-load row
  const bool rowOK = row < N;
  const float* Ap = A + (size_t)(rowOK ? row : 0) * K;
  const int KT = (K + 31) >> 5;

  f32x4 acc[8];
#pragma unroll
  for (int ct = 0; ct < 8; ++ct) acc[ct] = (f32x4){0.f, 0.f, 0.f, 0.f};

  for (int kt = 0; kt < KT; ++kt) {
    int kbase = kt * 32 + q * 8;
    float f[8];
    if (rowOK && kbase + 8 <= K) {
      float4 f0 = *(const float4*)(Ap + kbase);
      float4 f1 = *(const float4*)(Ap + kbase + 4);
      f[0] = f0.x; f[1] = f0.y; f[2] = f0.z; f[3] = f0.w;
      f[4] = f1.x; f[5] = f1.y; f[6] = f1.z; f[7] = f1.w;
    } else {
#pragma unroll
      for (int j = 0; j < 8; ++j)
        f[j] = (rowOK && kbase + j < K) ? Ap[kbase + j] : 0.f;
    }
    union { bf16x8 v; short s[8]; } ah, al;
#pragma unroll
    for (int j = 0; j < 8; ++j) {
      unsigned short hi = f2bf(f[j]);
      ah.s[j] = (short)hi;
      float hif = __uint_as_float((unsigned)hi << 16);
      al.s[j] = (short)f2bf(f[j] - hif);
    }
    const short* bh_base = whi + ((size_t)(kt * 8) * 64 + l) * 8;
    const short* bl_base = wlo + ((size_t)(kt * 8) * 64 + l) * 8;
#pragma unroll
    for (int ct = 0; ct < 8; ++ct) {
      bf16x8 bh = *(const bf16x8*)(bh_base + (size_t)ct * 512);
      bf16x8 bl = *(const bf16x8*)(bl_base + (size_t)ct * 512);
      acc[ct] = __builtin_amdgcn_mfma_f32_16x16x32_bf16(ah.v, bh, acc[ct], 0, 0, 0);
      acc[ct] = __builtin_amdgcn_mfma_f32_16x16x32_bf16(al.v, bh, acc[ct], 0, 0, 0);
      acc[ct] = __builtin_amdgcn_mfma_f32_16x16x32_bf16(ah.v, bl, acc[ct], 0, 0, 0);
    }
  }

  // epilogue: C/D row = rbase + q*4 + r, col = ct*16 + m
  int orow[4]; bool ok[4]; float on_[4];
#pragma unroll
  for (int r = 0; r < 4; ++r) {
    orow[r] = rbase + q * 4 + r;
    ok[r] = orow[r] < N;
    on_[r] = (out_bf && ok[r]) ? onorm[orow[r]] : 0.f;
  }
#pragma unroll
  for (int ct = 0; ct < 8; ++ct) {
    int col = ct * 16 + m;
    float bcol = bias[col];
    if (out_bf) {
#pragma unroll
      for (int r = 0; r < 4; ++r) {
        if (ok[r]) {
          float v = acc[ct][r] + bcol;
          v = v / (1.f + expf(-v));     // silu
          out_bf[(size_t)orow[r] * H + col] = f2bf(v * on_[r]);
        }
      }
    } else {
#pragma unroll
      for (int r = 0; r < 4; ++r) {
        if (ok[r]) {
          float v = acc[ct][r] + bcol;
          if (do_silu) v = v / (1.f + expf(-v));
          out_f[(size_t)orow[r] * H + col] = v;
        }
      }
    }
  }
}

// ---------------- gather (bf16 rows, onorm pre-folded): agg[v] = inorm[v]*sum h[src] ----------------
__global__ __launch_bounds__(64) void k_gather_bf(const unsigned* __restrict__ hb, // N x 64 words
                                                  const int* __restrict__ csr_src,
                                                  const int* __restrict__ row_ptr,
                                                  const float* __restrict__ inorm,
                                                  float* __restrict__ agg, int N) {
  int v = blockIdx.x;
  int t = threadIdx.x;
  int b = row_ptr[v], e = row_ptr[v + 1];
  float ax = 0.f, ay = 0.f;
  for (int i = b; i < e; ++i) {
    int s = csr_src[i];
    unsigned p = hb[(size_t)s * 64 + t];
    ax += __uint_as_float(p << 16);           // col 2t
    ay += __uint_as_float(p & 0xFFFF0000u);   // col 2t+1
  }
  float inn = inorm[v];
  *(float2*)(agg + (size_t)v * H + t * 2) = make_float2(ax * inn, ay * inn);
}

// ---------------- pooling: segment-sum over sorted graph_ids ----------------
__global__ __launch_bounds__(128) void k_pool(const float* __restrict__ h,
                                              const int* __restrict__ gid,
                                              float* pooled, int N) {
  int c = threadIdx.x;
  int v0 = blockIdx.x * 128;
  int vend = v0 + 128; if (vend > N) vend = N;
  if (v0 >= N) return;
  int cur = gid[v0];
  float acc = 0.f;
  for (int v = v0; v < vend; ++v) {
    int g = gid[v];
    if (g != cur) {
      atomicAdd(&pooled[(size_t)cur * H + c], acc);
      acc = 0.f; cur = g;
    }
    acc += h[(size_t)v * H + c];
  }
  atomicAdd(&pooled[(size_t)cur * H + c], acc);
}

// ---------------- final ff ----------------
__global__ __launch_bounds__(128) void k_ff(const float* __restrict__ pooled,
                                            const float* __restrict__ Wff,
                                            const float* __restrict__ bff,
                                            float* __restrict__ out, int G) {
  int g = blockIdx.x;
  int t = threadIdx.x;
  float v = pooled[(size_t)g * H + t] * Wff[t];
#pragma unroll
  for (int off = 32; off > 0; off >>= 1) v += __shfl_down(v, off, 64);
  __shared__ float red[2];
  if ((t & 63) == 0) red[t >> 6] = v;
  __syncthreads();
  if (t == 0) out[g] = red[0] + red[1] + bff[0];
}

extern "C" void kernel_launch(void* const* d_in, const int* in_sizes, int n_in,
                              void* d_out, int out_size, void* d_ws, size_t ws_size,
                              hipStream_t stream) {
  const float* x     = (const float*)d_in[0];
  const float* W_in  = (const float*)d_in[1];
  const float* b_in  = (const float*)d_in[2];
  const float* W_g0  = (const float*)d_in[3];
  const float* b_g0  = (const float*)d_in[4];
  const float* W_g1  = (const float*)d_in[5];
  const float* b_g1  = (const float*)d_in[6];
  const float* W_g2  = (const float*)d_in[7];
  const float* b_g2  = (const float*)d_in[8];
  const float* W_out = (const float*)d_in[9];
  const float* b_out = (const float*)d_in[10];
  const float* W_ff  = (const float*)d_in[11];
  const float* b_ff  = (const float*)d_in[12];
  const int* src = (const int*)d_in[13];
  const int* dst = (const int*)d_in[14];
  const int* gid = (const int*)d_in[15];
  float* out = (float*)d_out;

  const int N = in_sizes[15];          // 50000
  const int E = in_sizes[13];          // 600000
  const int K_IN = in_sizes[1] / H;    // 74
  const int G = out_size;              // 500

  char* ws = (char*)d_ws;
  size_t off = 0;
  auto alloc = [&](size_t bytes) -> void* {
    void* p = ws + off;
    off = (off + bytes + 255) & ~(size_t)255;
    return p;
  };
  float*          agg  = (float*)alloc((size_t)N * H * 4);          // fp32 gather out / h3 / hfinal
  unsigned short* hb   = (unsigned short*)alloc((size_t)N * H * 2); // bf16 gather in
  float* onorm   = (float*)alloc((size_t)N * 4);
  float* inorm   = (float*)alloc((size_t)N * 4);
  int*   ind     = (int*)alloc((size_t)N * 4);
  int*   row_ptr = (int*)alloc((size_t)(N + 1) * 4);
  int*   csr     = (int*)alloc((size_t)E * 4);
  float* pooled  = (float*)alloc((size_t)G * H * 4);
  int nb = (N + 1023) / 1024;
  int*   blk_sums = (int*)alloc((size_t)nb * 4);
  int*   blk_offs = (int*)alloc((size_t)nb * 4);

  // pre-split weight frags (hi/lo bf16, B-frag order)
  const int KT_IN = (K_IN + 31) >> 5;                       // 3 for K=74
  const int fr_in = KT_IN * 4096, fr_h = 4 * 4096;          // shorts per weight
  const int total_fr = fr_in + 4 * fr_h;
  short* whi_buf = (short*)alloc((size_t)total_fr * 2);
  short* wlo_buf = (short*)alloc((size_t)total_fr * 2);

  // packed hist partials alias agg (dead until first gather, long after CSR build):
  // nr*NCHUNK*RSIZE ints = 7*96*8192*4 = 22.0 MB <= N*H*4 = 25.6 MB.
  int nr = (N + RSIZE - 1) / RSIZE;
  int* ppack = (int*)agg;

  hipMemsetAsync(pooled, 0, (size_t)G * H * 4, stream);

  WSplitArgs wa;
  wa.W[0] = W_in;  wa.W[1] = W_g0; wa.W[2] = W_g1; wa.W[3] = W_g2; wa.W[4] = W_out;
  wa.K[0] = K_IN;  wa.K[1] = H;    wa.K[2] = H;    wa.K[3] = H;    wa.K[4] = H;
  wa.off[0] = 0;
  wa.off[1] = fr_in;
  for (int i = 2; i <= 5; ++i) wa.off[i] = wa.off[i - 1] + fr_h;
  k_wsplit<<<(total_fr + 255) / 256, 256, 0, stream>>>(wa, whi_buf, wlo_buf);

  k_hist<<<nr * NCHUNK, 256, 0, stream>>>(src, dst, ppack, E);
  k_reduce<<<(N + 255) / 256, 256, 0, stream>>>(ppack, ind, onorm, inorm, N);
  k_scan_blocks<<<nb, 1024, 0, stream>>>(ind, row_ptr, blk_sums, N);
  k_scan_tops<<<1, 1024, 0, stream>>>(blk_sums, blk_offs, row_ptr, nb, N);
  k_scan_add<<<(N + 255) / 256, 256, 0, stream>>>(row_ptr, blk_offs, N);
  k_fill_nr<<<nr * NCHUNK, 256, 0, stream>>>(src, dst, row_ptr, ppack, csr, N, E);

  int gblk = (N + 63) / 64;
  short* whi_in = whi_buf + wa.off[0]; short* wlo_in = wlo_buf + wa.off[0];
  short* whi_g0 = whi_buf + wa.off[1]; short* wlo_g0 = wlo_buf + wa.off[1];
  short* whi_g1 = whi_buf + wa.off[2]; short* wlo_g1 = wlo_buf + wa.off[2];
  short* whi_g2 = whi_buf + wa.off[3]; short* wlo_g2 = wlo_buf + wa.off[3];
  short* whi_o  = whi_buf + wa.off[4]; short* wlo_o  = wlo_buf + wa.off[4];

  // embedding_in: hb0 = bf16(silu(x @ W_in + b_in) * onorm)
  k_gemm_mfma<<<gblk, 256, 0, stream>>>(x, whi_in, wlo_in, b_in, onorm, nullptr, hb, N, K_IN, 1);

  // layer 0
  k_gather_bf<<<N, 64, 0, stream>>>((const unsigned*)hb, csr, row_ptr, inorm, agg, N);
  k_gemm_mfma<<<gblk, 256, 0, stream>>>(agg, whi_g0, wlo_g0, b_g0, onorm, nullptr, hb, N, H, 1);
  // layer 1
  k_gather_bf<<<N, 64, 0, stream>>>((const unsigned*)hb, csr, row_ptr, inorm, agg, N);
  k_gemm_mfma<<<gblk, 256, 0, stream>>>(agg, whi_g1, wlo_g1, b_g1, onorm, nullptr, hb, N, H, 1);
  // layer 2: output feeds GEMM (sequential) -> fp32 in place
  k_gather_bf<<<N, 64, 0, stream>>>((const unsigned*)hb, csr, row_ptr, inorm, agg, N);
  k_gemm_mfma<<<gblk, 256, 0, stream>>>(agg, whi_g2, wlo_g2, b_g2, nullptr, agg, nullptr, N, H, 1);

  // embedding_out (no act), in-place
  k_gemm_mfma<<<gblk, 256, 0, stream>>>(agg, whi_o, wlo_o, b_out, nullptr, agg, nullptr, N, H, 0);

  k_pool<<<(N + 127) / 128, 128, 0, stream>>>(agg, gid, pooled, N);
  k_ff<<<G, 128, 0, stream>>>(pooled, W_ff, b_ff, out, G);
}